// Round 1
// baseline (350.439 us; speedup 1.0000x reference)
//
#include <hip/hip_runtime.h>
#include <math.h>

// Problem: B=4, S=4096, H=2048, E=64, K=8; T = 16384 tokens.
#define HDIM 2048
#define TTOK 16384
#define NEXP 64
#define TOPK 8
#define SLEN 4096
#define NBATCH 4

// Output layout (flat, float32):
#define OFF_W    131072
#define OFF_LOSS 262144
#define OFF_LOAD 262145

// ws layout (float offsets): Pacc[4][64] @0, Cacc[4][64] @256, counter @512,
// Wt [2048][64] @1024. No k-split partials anymore (fused epilogue).
#define WS_PACC 0
#define WS_CACC 256
#define WS_CNT  512
#define WS_WT   1024

// ---------------------------------------------------------------------------
// LDS-tiled transpose W [64][2048] -> Wt [2048][64] (R2-proven, unchanged).
__global__ __launch_bounds__(256) void transpose_w(const float* __restrict__ W,
                                                   float* __restrict__ Wt) {
  __shared__ float tile[64][65];
  const int tid = threadIdx.x;
  const int k0 = blockIdx.x * 64;
  {
    const int kc = (tid & 15) << 2;
    const int er = tid >> 4;
#pragma unroll
    for (int i = 0; i < 4; ++i) {
      int e = er + i * 16;
      float4 v = *(const float4*)(W + (size_t)e * HDIM + k0 + kc);
      tile[e][kc + 0] = v.x; tile[e][kc + 1] = v.y;
      tile[e][kc + 2] = v.z; tile[e][kc + 3] = v.w;
    }
  }
  __syncthreads();
  {
    const int e4 = (tid & 15) << 2;
    const int kr = tid >> 4;
#pragma unroll
    for (int i = 0; i < 4; ++i) {
      int k = kr + i * 16;
      float4 v;
      v.x = tile[e4 + 0][k]; v.y = tile[e4 + 1][k];
      v.z = tile[e4 + 2][k]; v.w = tile[e4 + 3][k];
      *(float4*)(Wt + (size_t)(k0 + k) * NEXP + e4) = v;
    }
  }
}

// ---------------------------------------------------------------------------
// Fused gate: grid 256 x 512 thr. Block = 64 tokens x 64 experts x full K.
// Wave w (0..7): experts [8w, 8w+8), lane = token. No k-split, no partials.
// x tile [64 tok][32 k] in LDS, slot = granule ^ (row&7) (R2-verified
// conflict-free on store and b128 read). Double-buffered, one barrier/tile,
// register prefetch depth 2 (only 2 waves/SIMD resident -> need the slack).
// Per-acc k strictly ascending (same FP order family as R2).
// Epilogue in-block: wave0 does top-8 + outputs + Cacc, wave1 concurrently
// does rinv + per-expert P + Pacc. Loss finalized by last block (counter).
__global__ __launch_bounds__(512) void gate_fused(
    const float* __restrict__ x,    // [16384][2048]
    const float* __restrict__ Wt,   // [2048][64]
    const float* __restrict__ bias, // [64]
    float* __restrict__ out, float* __restrict__ Pacc,
    float* __restrict__ Cacc, int* __restrict__ counter) {
  __shared__ float xs[2][64 * 32];   // 16 KB double buffer
  __shared__ float le[64 * 65];      // logits [token][expert], padded
  __shared__ float sgm[64 * 65];     // sigmoid(logits), padded
  __shared__ float rsum[8 * 64];     // per-wave partial row sums of sigmoids
  __shared__ float rinvs[64];
  __shared__ float biasl[64];
  __shared__ unsigned csum[64];
  __shared__ int lastf;

  const int tid = threadIdx.x;
  const int lane = tid & 63;
  const int wv = __builtin_amdgcn_readfirstlane(tid >> 6);  // 0..7
  const int tok0 = blockIdx.x << 6;  // 64 tokens/block, 256 blocks

  if (tid < 64) { csum[tid] = 0u; biasl[tid] = bias[tid]; }

  // staging: thread -> row r0 (0..63), granule sgr (16B), swizzled slot
  const int r0 = tid >> 3;
  const int sgr = tid & 7;
  const int sslot = (sgr ^ (r0 & 7)) << 2;
  const float* xp = x + (size_t)(tok0 + r0) * HDIM + (sgr << 2);
  float4 aA = *(const float4*)xp;           // tile 0
  float4 aB = *(const float4*)(xp + 32);    // tile 1

  const int rbase = lane << 5;
  const int rs = lane & 7;  // == token & 7
  float acc[8];
#pragma unroll
  for (int j = 0; j < 8; ++j) acc[j] = 0.f;
  const float* wb = Wt + (wv << 3);

  constexpr int NT = HDIM / 32;  // 64 tiles
  for (int kt = 0; kt < NT; ++kt) {
    float* xb = &xs[kt & 1][0];
    *(float4*)&xb[(r0 << 5) + sslot] = aA;
    __syncthreads();  // single barrier/tile (R2-proven dbuf)
    aA = aB;
    if (kt + 2 < NT) aB = *(const float4*)(xp + ((kt + 2) << 5));
    const float* wkb = wb + ((size_t)(kt << 5) << 6);
#pragma unroll
    for (int c = 0; c < 8; ++c) {
      // slot (c^rs) of own row holds logical granule c -> k ascending
      float4 xv = *(const float4*)&xb[rbase + ((c ^ rs) << 2)];
      const float xf[4] = {xv.x, xv.y, xv.z, xv.w};
#pragma unroll
      for (int q = 0; q < 4; ++q) {
        const float* wr = wkb + (((c << 2) + q) << 6);  // uniform -> s_load
#pragma unroll
        for (int j = 0; j < 8; ++j) acc[j] = fmaf(xf[q], wr[j], acc[j]);
      }
    }
  }

  // publish logits + sigmoids + per-wave row-sum partials (scalar stores,
  // stride 65: bank = (lane + col) % 32 -> 2-way max, free)
  {
    float rs8 = 0.f;
    const int lrow = lane * 65 + (wv << 3);
#pragma unroll
    for (int j = 0; j < 8; ++j) {
      float s = 1.f / (1.f + expf(-acc[j]));
      le[lrow + j] = acc[j];
      sgm[lrow + j] = s;
      rs8 += s;
    }
    rsum[(wv << 6) + lane] = rs8;
  }
  __syncthreads();

  const int b = (int)(blockIdx.x >> 6);  // batch index (64 blocks/batch)

  if (wv == 0) {
    // per-token top-8 (lane = token), proven scan structure
    const int t = lane;
    float bl[64];
#pragma unroll
    for (int e = 0; e < NEXP; ++e) bl[e] = le[t * 65 + e] + biasl[e];

    unsigned long long chosen = 0ull;
    int i8[TOPK];
    float w8[TOPK];
    float wsum = 0.f;
#pragma unroll
    for (int j = 0; j < TOPK; ++j) {
      float best = -1e30f;
      int bi = 0;
#pragma unroll
      for (int e = 0; e < NEXP; ++e) {
        bool ok = (((chosen >> e) & 1ull) == 0ull) && (bl[e] > best);
        if (ok) { best = bl[e]; bi = e; }
      }
      chosen |= (1ull << bi);
      float sc = sgm[t * 65 + bi];  // exact sigmoid of raw logit
      i8[j] = bi;
      w8[j] = sc;
      wsum += sc;
    }
    const float inv = 1.f / (wsum + 1e-10f);
    const int tt = tok0 + t;
    float4 o;
    o.x = (float)i8[0]; o.y = (float)i8[1]; o.z = (float)i8[2]; o.w = (float)i8[3];
    *(float4*)(out + (size_t)tt * TOPK) = o;
    o.x = (float)i8[4]; o.y = (float)i8[5]; o.z = (float)i8[6]; o.w = (float)i8[7];
    *(float4*)(out + (size_t)tt * TOPK + 4) = o;
    o.x = w8[0] * inv; o.y = w8[1] * inv; o.z = w8[2] * inv; o.w = w8[3] * inv;
    *(float4*)(out + OFF_W + (size_t)tt * TOPK) = o;
    o.x = w8[4] * inv; o.y = w8[5] * inv; o.z = w8[6] * inv; o.w = w8[7] * inv;
    *(float4*)(out + OFF_W + (size_t)tt * TOPK + 4) = o;
#pragma unroll
    for (int j = 0; j < TOPK; ++j) atomicAdd(&csum[i8[j]], 1u);
    // wave-lockstep: all lanes' LDS atomics precede this read in program order
    atomicAdd(&Cacc[(b << 6) + lane], (float)csum[lane]);
  } else if (wv == 1) {
    // rinv per token, then per-expert P partial (independent of top-8)
    const int t = lane;
    float ss = 0.f;
#pragma unroll
    for (int w = 0; w < 8; ++w) ss += rsum[(w << 6) + t];
    rinvs[t] = 1.f / (ss + 1e-10f);
    // same-wave LDS RAW -> ordered via lgkmcnt
    float p = 0.f;
    for (int t2 = 0; t2 < 64; ++t2) p += sgm[t2 * 65 + lane] * rinvs[t2];
    atomicAdd(&Pacc[(b << 6) + lane], p);
  }

  __syncthreads();
  __threadfence();
  if (tid == 0) {
    int old = __hip_atomic_fetch_add(counter, 1, __ATOMIC_ACQ_REL,
                                     __HIP_MEMORY_SCOPE_AGENT);
    lastf = (old == 255) ? 1 : 0;
  }
  __syncthreads();

  if (lastf && tid < 64) {
    const int e = tid;
    float load = 0.f, partl = 0.f;
#pragma unroll
    for (int bb = 0; bb < NBATCH; ++bb) {
      float c = __hip_atomic_load(&Cacc[(bb << 6) + e], __ATOMIC_RELAXED,
                                  __HIP_MEMORY_SCOPE_AGENT);
      float p = __hip_atomic_load(&Pacc[(bb << 6) + e], __ATOMIC_RELAXED,
                                  __HIP_MEMORY_SCOPE_AGENT);
      load += c;
      partl += (c * (1.f / (TOPK * (float)SLEN))) * (p * (1.f / (float)SLEN));
    }
    out[OFF_LOAD + e] = load;
#pragma unroll
    for (int off = 32; off; off >>= 1) partl += __shfl_down(partl, off);
    if (e == 0) out[OFF_LOSS] = 0.01f * partl * (1.f / (float)NBATCH);
  }
}

// ---------------------------------------------------------------------------
extern "C" void kernel_launch(void* const* d_in, const int* in_sizes, int n_in,
                              void* d_out, int out_size, void* d_ws, size_t ws_size,
                              hipStream_t stream) {
  const float* x = (const float*)d_in[0];     // [4,4096,2048]
  const float* W = (const float*)d_in[1];     // [64,2048]
  const float* bias = (const float*)d_in[2];  // [64]
  float* out = (float*)d_out;

  float* ws = (float*)d_ws;
  float* Pacc = ws + WS_PACC;
  float* Cacc = ws + WS_CACC;
  int* counter = (int*)(ws + WS_CNT);
  float* Wt = ws + WS_WT;

  hipMemsetAsync(ws, 0, WS_WT * sizeof(float), stream);
  transpose_w<<<32, 256, 0, stream>>>(W, Wt);
  gate_fused<<<256, 512, 0, stream>>>(x, Wt, bias, out, Pacc, Cacc, counter);
}

// Round 2
// 318.114 us; speedup vs baseline: 1.1016x; 1.1016x over previous
//
#include <hip/hip_runtime.h>
#include <math.h>

// Problem: B=4, S=4096, H=2048, E=64, K=8; T = 16384 tokens.
#define HDIM 2048
#define TTOK 16384
#define NEXP 64
#define TOPK 8
#define SLEN 4096
#define NBATCH 4

// Output layout (flat, float32):
#define OFF_W    131072
#define OFF_LOSS 262144
#define OFF_LOAD 262145

// ws layout (float offsets): Pacc[4][64] @0, Cacc[4][64] @256, counter @512,
// Wt [2048][64] @1024. Fully fused: no k-split partials in global memory.
#define WS_PACC 0
#define WS_CACC 256
#define WS_CNT  512
#define WS_WT   1024

// ---------------------------------------------------------------------------
// LDS-tiled transpose W [64][2048] -> Wt [2048][64] (R2-proven, unchanged).
__global__ __launch_bounds__(256) void transpose_w(const float* __restrict__ W,
                                                   float* __restrict__ Wt) {
  __shared__ float tile[64][65];
  const int tid = threadIdx.x;
  const int k0 = blockIdx.x * 64;
  {
    const int kc = (tid & 15) << 2;
    const int er = tid >> 4;
#pragma unroll
    for (int i = 0; i < 4; ++i) {
      int e = er + i * 16;
      float4 v = *(const float4*)(W + (size_t)e * HDIM + k0 + kc);
      tile[e][kc + 0] = v.x; tile[e][kc + 1] = v.y;
      tile[e][kc + 2] = v.z; tile[e][kc + 3] = v.w;
    }
  }
  __syncthreads();
  {
    const int e4 = (tid & 15) << 2;
    const int kr = tid >> 4;
#pragma unroll
    for (int i = 0; i < 4; ++i) {
      int k = kr + i * 16;
      float4 v;
      v.x = tile[e4 + 0][k]; v.y = tile[e4 + 1][k];
      v.z = tile[e4 + 2][k]; v.w = tile[e4 + 3][k];
      *(float4*)(Wt + (size_t)(k0 + k) * NEXP + e4) = v;
    }
  }
}

// ---------------------------------------------------------------------------
// Fused gate: grid 256 x 1024 thr = 16 waves = 4 expert-groups x 4 k-quarters.
// Block = 64 tokens x 64 experts x full K. Wave (eg,kq): experts
// [16eg,16eg+16) over k-quarter kq (granules kq*4..kq*4+4 of each tile).
// Thread: 16 accs, lane = token. 4 waves/SIMD (vs 2 in R1) and 16 FMAs per
// s_load_dwordx16 (vs 8 per dwordx8) to hide scalar-load latency.
// x tile [64 tok][64 k], slot = granule ^ (row&15): conflict-free on float4
// store (each bank x8/wave = 1KB minimum) and b128 read (16-slot permutation).
// Double-buffered, one barrier/tile, prefetch depth 2.
// k-quarter partials combined in LDS, fixed order (p0+p1)+(p2+p3), k
// ascending within quarter -> deterministic (KS=4 FP-order family).
// Epilogue (proven): wave0 top-8 + outputs + Cacc; wave1 rinv + P + Pacc;
// last block (device counter) finalizes load/loss.
__global__ __launch_bounds__(1024, 4) void gate_fused(
    const float* __restrict__ x,    // [16384][2048]
    const float* __restrict__ Wt,   // [2048][64]
    const float* __restrict__ bias, // [64]
    float* __restrict__ out, float* __restrict__ Pacc,
    float* __restrict__ Cacc, int* __restrict__ counter) {
  __shared__ float xs[2][64 * 64];   // 32 KB double buffer
  __shared__ float pac[4 * 64 * 65]; // 66.6 KB quarter partials [kq][tok][e]
                                     // (quarters 0/1 overlaid by le/sgm later)
  __shared__ float rsum[4 * 64];     // per-expert-group row sums of sigmoids
  __shared__ float rinvs[64];
  __shared__ float biasl[64];
  __shared__ unsigned csum[64];
  __shared__ int lastf;

  const int tid = threadIdx.x;
  const int lane = tid & 63;
  const int wv = __builtin_amdgcn_readfirstlane(tid >> 6);  // 0..15
  const int eg = wv & 3;   // expert group: [16eg, 16eg+16)
  const int kq = wv >> 2;  // k-quarter 0..3
  const int tok0 = blockIdx.x << 6;  // 64 tokens/block, 256 blocks

  if (tid < 64) { csum[tid] = 0u; biasl[tid] = bias[tid]; }

  // staging: thread -> row r0 (0..63), granule sg (0..15, 16B), swizzled slot
  const int r0 = tid >> 4;
  const int sg = tid & 15;
  const int sslot = (sg ^ (r0 & 15)) << 2;
  const float* xp = x + (size_t)(tok0 + r0) * HDIM + (sg << 2);
  float4 aA = *(const float4*)xp;           // tile 0
  float4 aB = *(const float4*)(xp + 64);    // tile 1

  const int rbase = lane << 6;
  const int rs = lane & 15;  // == token & 15
  float acc[16];
#pragma unroll
  for (int j = 0; j < 16; ++j) acc[j] = 0.f;
  const float* wb = Wt + (eg << 4);

  constexpr int NT = HDIM / 64;  // 32 tiles of 64 k
  for (int kt = 0; kt < NT; ++kt) {
    float* xb = &xs[kt & 1][0];
    *(float4*)&xb[(r0 << 6) + sslot] = aA;
    __syncthreads();  // single barrier/tile (dbuf-proven)
    aA = aB;
    if (kt + 2 < NT) aB = *(const float4*)(xp + ((kt + 2) << 6));
    // weight rows for this wave's quarter: k = kt*64 + kq*16 + c*4 + q
    const float* wkb = wb + ((size_t)((kt << 6) + (kq << 4)) << 6);
#pragma unroll
    for (int c = 0; c < 4; ++c) {
      const int g = (kq << 2) + c;  // logical granule in tile
      float4 xv = *(const float4*)&xb[rbase + ((g ^ rs) << 2)];
      const float xf[4] = {xv.x, xv.y, xv.z, xv.w};
#pragma unroll
      for (int q = 0; q < 4; ++q) {
        const float* wr = wkb + (((c << 2) + q) << 6);  // uniform -> s_load_x16
#pragma unroll
        for (int j = 0; j < 16; ++j) acc[j] = fmaf(xf[q], wr[j], acc[j]);
      }
    }
  }

  // publish quarter partials: pac[kq][tok][e], stride 65 (bank = tok+e, free)
  {
    const int base = kq * 4160 + lane * 65 + (eg << 4);
#pragma unroll
    for (int j = 0; j < 16; ++j) pac[base + j] = acc[j];
  }
  __syncthreads();

  float* le = pac;            // overlay quarter 0 (dead after combine)
  float* sgm = pac + 4160;    // overlay quarter 1

  if (kq == 0) {
    // combine quarters (deterministic pairwise) + sigmoid + publish.
    // Each thread reads/writes only its own (lane, eg*16+j) slots -> no race.
    const int rb = lane * 65 + (eg << 4);
    float fl[16];
#pragma unroll
    for (int j = 0; j < 16; ++j) {
      float p0 = pac[rb + j];
      float p1 = pac[4160 + rb + j];
      float p2 = pac[8320 + rb + j];
      float p3 = pac[12480 + rb + j];
      fl[j] = (p0 + p1) + (p2 + p3);
    }
    float rs16 = 0.f;
#pragma unroll
    for (int j = 0; j < 16; ++j) {
      float s = 1.f / (1.f + expf(-fl[j]));
      le[rb + j] = fl[j];
      sgm[rb + j] = s;
      rs16 += s;
    }
    rsum[(eg << 6) + lane] = rs16;
  }
  __syncthreads();

  const int b = (int)(blockIdx.x >> 6);  // batch index (64 blocks/batch)

  if (wv == 0) {
    // per-token top-8 (lane = token), proven scan structure
    const int t = lane;
    float bl[64];
#pragma unroll
    for (int e = 0; e < NEXP; ++e) bl[e] = le[t * 65 + e] + biasl[e];

    unsigned long long chosen = 0ull;
    int i8[TOPK];
    float w8[TOPK];
    float wsum = 0.f;
#pragma unroll
    for (int j = 0; j < TOPK; ++j) {
      float best = -1e30f;
      int bi = 0;
#pragma unroll
      for (int e = 0; e < NEXP; ++e) {
        bool ok = (((chosen >> e) & 1ull) == 0ull) && (bl[e] > best);
        if (ok) { best = bl[e]; bi = e; }
      }
      chosen |= (1ull << bi);
      float sc = sgm[t * 65 + bi];  // exact sigmoid of raw logit
      i8[j] = bi;
      w8[j] = sc;
      wsum += sc;
    }
    const float inv = 1.f / (wsum + 1e-10f);
    const int tt = tok0 + t;
    float4 o;
    o.x = (float)i8[0]; o.y = (float)i8[1]; o.z = (float)i8[2]; o.w = (float)i8[3];
    *(float4*)(out + (size_t)tt * TOPK) = o;
    o.x = (float)i8[4]; o.y = (float)i8[5]; o.z = (float)i8[6]; o.w = (float)i8[7];
    *(float4*)(out + (size_t)tt * TOPK + 4) = o;
    o.x = w8[0] * inv; o.y = w8[1] * inv; o.z = w8[2] * inv; o.w = w8[3] * inv;
    *(float4*)(out + OFF_W + (size_t)tt * TOPK) = o;
    o.x = w8[4] * inv; o.y = w8[5] * inv; o.z = w8[6] * inv; o.w = w8[7] * inv;
    *(float4*)(out + OFF_W + (size_t)tt * TOPK + 4) = o;
#pragma unroll
    for (int j = 0; j < TOPK; ++j) atomicAdd(&csum[i8[j]], 1u);
    // wave-lockstep: all lanes' LDS atomics precede this read in program order
    atomicAdd(&Cacc[(b << 6) + lane], (float)csum[lane]);
  } else if (wv == 1) {
    // rinv per token, then per-expert P partial (independent of top-8)
    const int t = lane;
    float ss = 0.f;
#pragma unroll
    for (int w = 0; w < 4; ++w) ss += rsum[(w << 6) + t];
    rinvs[t] = 1.f / (ss + 1e-10f);
    // same-wave LDS RAW -> ordered via lgkmcnt
    float p = 0.f;
    for (int t2 = 0; t2 < 64; ++t2) p += sgm[t2 * 65 + lane] * rinvs[t2];
    atomicAdd(&Pacc[(b << 6) + lane], p);
  }

  __syncthreads();
  __threadfence();
  if (tid == 0) {
    int old = __hip_atomic_fetch_add(counter, 1, __ATOMIC_ACQ_REL,
                                     __HIP_MEMORY_SCOPE_AGENT);
    lastf = (old == 255) ? 1 : 0;
  }
  __syncthreads();

  if (lastf && tid < 64) {
    const int e = tid;
    float load = 0.f, partl = 0.f;
#pragma unroll
    for (int bb = 0; bb < NBATCH; ++bb) {
      float c = __hip_atomic_load(&Cacc[(bb << 6) + e], __ATOMIC_RELAXED,
                                  __HIP_MEMORY_SCOPE_AGENT);
      float p = __hip_atomic_load(&Pacc[(bb << 6) + e], __ATOMIC_RELAXED,
                                  __HIP_MEMORY_SCOPE_AGENT);
      load += c;
      partl += (c * (1.f / (TOPK * (float)SLEN))) * (p * (1.f / (float)SLEN));
    }
    out[OFF_LOAD + e] = load;
#pragma unroll
    for (int off = 32; off; off >>= 1) partl += __shfl_down(partl, off);
    if (e == 0) out[OFF_LOSS] = 0.01f * partl * (1.f / (float)NBATCH);
  }
}

// ---------------------------------------------------------------------------
extern "C" void kernel_launch(void* const* d_in, const int* in_sizes, int n_in,
                              void* d_out, int out_size, void* d_ws, size_t ws_size,
                              hipStream_t stream) {
  const float* x = (const float*)d_in[0];     // [4,4096,2048]
  const float* W = (const float*)d_in[1];     // [64,2048]
  const float* bias = (const float*)d_in[2];  // [64]
  float* out = (float*)d_out;

  float* ws = (float*)d_ws;
  float* Pacc = ws + WS_PACC;
  float* Cacc = ws + WS_CACC;
  int* counter = (int*)(ws + WS_CNT);
  float* Wt = ws + WS_WT;

  hipMemsetAsync(ws, 0, WS_WT * sizeof(float), stream);
  transpose_w<<<32, 256, 0, stream>>>(W, Wt);
  gate_fused<<<256, 1024, 0, stream>>>(x, Wt, bias, out, Pacc, Cacc, counter);
}

// Round 3
// 287.050 us; speedup vs baseline: 1.2208x; 1.1082x over previous
//
#include <hip/hip_runtime.h>
#include <math.h>

// Problem: B=4, S=4096, H=2048, E=64, K=8; T = 16384 tokens.
#define HDIM 2048
#define TTOK 16384
#define NEXP 64
#define TOPK 8
#define SLEN 4096
#define NBATCH 4

// Output layout (flat, float32):
#define OFF_W    131072
#define OFF_LOSS 262144
#define OFF_LOAD 262145

// ws layout (float offsets): Pacc[4][64] @0, Cacc[4][64] @256, counter @512,
// Wh bf16[64][2048] @1024 (=65536 floats), Wl bf16[64][2048] @66560.
#define WS_PACC 0
#define WS_CACC 256
#define WS_CNT  512
#define WS_WH   1024
#define WS_WL   (1024 + 65536)

using s16x8 = __attribute__((ext_vector_type(8))) short;   // 8 bf16 (4 VGPR)
using f32x4 = __attribute__((ext_vector_type(4))) float;   // MFMA acc

// bf16 round-to-nearest-even of fp32 (finite inputs only)
__device__ __forceinline__ unsigned bfh(float v) {
  unsigned b = __float_as_uint(v);
  return (b + 0x7FFFu + ((b >> 16) & 1u)) >> 16;
}

// split float4 into hi/lo bf16 planes, packed 4x bf16 per uint2
__device__ __forceinline__ void split4(float4 v, uint2* hi, uint2* lo) {
  unsigned h0 = bfh(v.x), h1 = bfh(v.y), h2 = bfh(v.z), h3 = bfh(v.w);
  float r0 = v.x - __uint_as_float(h0 << 16);
  float r1 = v.y - __uint_as_float(h1 << 16);
  float r2 = v.z - __uint_as_float(h2 << 16);
  float r3 = v.w - __uint_as_float(h3 << 16);
  unsigned l0 = bfh(r0), l1 = bfh(r1), l2 = bfh(r2), l3 = bfh(r3);
  *hi = make_uint2(h0 | (h1 << 16), h2 | (h3 << 16));
  *lo = make_uint2(l0 | (l1 << 16), l2 | (l3 << 16));
}

// ---------------------------------------------------------------------------
// W fp32 [64][2048] -> Wh/Wl bf16 planes [64][2048] (replaces transpose;
// MFMA consumes W in original [e][k] orientation).
__global__ __launch_bounds__(256) void prep_w(const float* __restrict__ W,
                                              ushort* __restrict__ Wh,
                                              ushort* __restrict__ Wl) {
  const int i = (blockIdx.x * 256 + threadIdx.x) << 2;  // grid 128 -> 131072
  float4 v = *(const float4*)(W + i);
  uint2 hp, lp;
  split4(v, &hp, &lp);
  *(uint2*)(Wh + i) = hp;
  *(uint2*)(Wl + i) = lp;
}

// ---------------------------------------------------------------------------
// Fused gate via 3-term bf16-split MFMA.
// grid 256 x 1024 thr = 16 waves = 4 mt x 4 nt tiles of 16x16 over the
// 64 tok x 64 expert block output; full K per wave (no k-split partials).
// Per K=64 step: stage x (fp32->bf16 hi/lo) and Wh/Wl into LDS, 1 barrier
// (R2-proven dbuf), then each wave: 8 ds_read_b128 frags + 6 MFMA.
// acc += xl*wh + xh*wl + xh*wh  (xl*wl ~2^-18 rel, dropped).
// LDS tile [row][64 k] bf16, 16B granule g=k>>3 stored at slot g^(row&7):
// frag b128 reads are conflict-free (16-lane group covers all 32 banks).
// A/B frags use identical lane->k math => HW k-permutation cancels.
// C/D mapping (m89-verified): col=lane&15 (expert), row=(lane>>4)*4+reg (tok).
// Epilogue: wave0 top-8 + outputs + Cacc; wave1 rowsum/rinv + P + Pacc;
// last block (device counter) finalizes load/loss.
__global__ __launch_bounds__(1024) void gate_fused(
    const float* __restrict__ x,     // [16384][2048]
    const ushort* __restrict__ Whg,  // [64][2048] bf16
    const ushort* __restrict__ Wlg,  // [64][2048] bf16
    const float* __restrict__ bias,  // [64]
    float* __restrict__ out, float* __restrict__ Pacc,
    float* __restrict__ Cacc, int* __restrict__ counter) {
  __shared__ ushort XhL[2][4096];  // [64 tok][64 k] swizzled, 8 KB each
  __shared__ ushort XlL[2][4096];
  __shared__ ushort WhL[2][4096];  // [64 e][64 k] swizzled
  __shared__ ushort WlL[2][4096];
  __shared__ float le[64 * 65];    // logits [token][expert], padded
  __shared__ float sgm[64 * 65];   // sigmoid(logits), padded
  __shared__ float rinvs[64];
  __shared__ float biasl[64];
  __shared__ unsigned csum[64];
  __shared__ int lastf;

  const int tid = threadIdx.x;
  const int lane = tid & 63;
  const int wv = __builtin_amdgcn_readfirstlane(tid >> 6);  // 0..15
  const int tok0 = blockIdx.x << 6;  // 64 tokens/block, 256 blocks

  if (tid < 64) { csum[tid] = 0u; biasl[tid] = bias[tid]; }

  // ---- staging map: thread -> row (t>>4, 0..63), k-offset (t&15)*4 ----
  const int srow = tid >> 4;
  const int skq = (tid & 15) << 2;                      // 0..60, 4-aligned
  const int sdst = (srow << 6) + (((skq >> 3) ^ (srow & 7)) << 3) +
                   (((skq >> 2) & 1) << 2);             // ushort index
  const float* xsrc = x + (size_t)(tok0 + srow) * HDIM + skq;
  const ushort* whsrc = Whg + ((size_t)srow << 11) + skq;
  const ushort* wlsrc = Wlg + ((size_t)srow << 11) + skq;

  float4 xA = *(const float4*)xsrc;            // step 0
  float4 xB = *(const float4*)(xsrc + 64);     // step 1
  uint2 whA = *(const uint2*)whsrc;
  uint2 whB = *(const uint2*)(whsrc + 64);
  uint2 wlA = *(const uint2*)wlsrc;
  uint2 wlB = *(const uint2*)(wlsrc + 64);

  // ---- MFMA frag addressing (wave = (mt, nt) 16x16 tile) ----
  const int mt = wv >> 2, nt = wv & 3;
  const int fl = lane & 15, fg = lane >> 4;
  const int arow = (mt << 4) + fl;   // token row
  const int brow = (nt << 4) + fl;   // expert row
  const int ab0 = (arow << 6) + ((fg ^ (arow & 7)) << 3);        // k 0..31
  const int ab1 = (arow << 6) + (((fg + 4) ^ (arow & 7)) << 3);  // k 32..63
  const int bb0 = (brow << 6) + ((fg ^ (brow & 7)) << 3);
  const int bb1 = (brow << 6) + (((fg + 4) ^ (brow & 7)) << 3);

  f32x4 acc = {0.f, 0.f, 0.f, 0.f};

  constexpr int NT = HDIM / 64;  // 32 steps of K=64
  for (int kt = 0; kt < NT; ++kt) {
    const int cur = kt & 1;
    {  // convert + stage x, stage w (writes to buf[cur])
      uint2 hp, lp;
      split4(xA, &hp, &lp);
      *(uint2*)&XhL[cur][sdst] = hp;
      *(uint2*)&XlL[cur][sdst] = lp;
      *(uint2*)&WhL[cur][sdst] = whA;
      *(uint2*)&WlL[cur][sdst] = wlA;
    }
    __syncthreads();  // single barrier/step (dbuf-proven)
    xA = xB; whA = whB; wlA = wlB;
    if (kt + 2 < NT) {
      xB = *(const float4*)(xsrc + ((kt + 2) << 6));
      whB = *(const uint2*)(whsrc + ((kt + 2) << 6));
      wlB = *(const uint2*)(wlsrc + ((kt + 2) << 6));
    }
    s16x8 ah0 = *(const s16x8*)&XhL[cur][ab0];
    s16x8 al0 = *(const s16x8*)&XlL[cur][ab0];
    s16x8 bh0 = *(const s16x8*)&WhL[cur][bb0];
    s16x8 bl0 = *(const s16x8*)&WlL[cur][bb0];
    acc = __builtin_amdgcn_mfma_f32_16x16x32_bf16(al0, bh0, acc, 0, 0, 0);
    acc = __builtin_amdgcn_mfma_f32_16x16x32_bf16(ah0, bl0, acc, 0, 0, 0);
    acc = __builtin_amdgcn_mfma_f32_16x16x32_bf16(ah0, bh0, acc, 0, 0, 0);
    s16x8 ah1 = *(const s16x8*)&XhL[cur][ab1];
    s16x8 al1 = *(const s16x8*)&XlL[cur][ab1];
    s16x8 bh1 = *(const s16x8*)&WhL[cur][bb1];
    s16x8 bl1 = *(const s16x8*)&WlL[cur][bb1];
    acc = __builtin_amdgcn_mfma_f32_16x16x32_bf16(al1, bh1, acc, 0, 0, 0);
    acc = __builtin_amdgcn_mfma_f32_16x16x32_bf16(ah1, bl1, acc, 0, 0, 0);
    acc = __builtin_amdgcn_mfma_f32_16x16x32_bf16(ah1, bh1, acc, 0, 0, 0);
  }

  // ---- publish logits + sigmoids (C/D layout: row=(fg)*4+r, col=fl) ----
  {
    const int trow = (mt << 4) + (fg << 2);
    const int ecol = (nt << 4) + fl;
#pragma unroll
    for (int r = 0; r < 4; ++r) {
      float lg = acc[r];
      le[(trow + r) * 65 + ecol] = lg;
      sgm[(trow + r) * 65 + ecol] = 1.f / (1.f + expf(-lg));
    }
  }
  __syncthreads();

  const int b = (int)(blockIdx.x >> 6);  // batch index (64 blocks/batch)

  if (wv == 0) {
    // per-token top-8 (lane = token), proven scan structure
    const int t = lane;
    float bl[64];
#pragma unroll
    for (int e = 0; e < NEXP; ++e) bl[e] = le[t * 65 + e] + biasl[e];

    unsigned long long chosen = 0ull;
    int i8[TOPK];
    float w8[TOPK];
    float wsum = 0.f;
#pragma unroll
    for (int j = 0; j < TOPK; ++j) {
      float best = -1e30f;
      int bi = 0;
#pragma unroll
      for (int e = 0; e < NEXP; ++e) {
        bool ok = (((chosen >> e) & 1ull) == 0ull) && (bl[e] > best);
        if (ok) { best = bl[e]; bi = e; }
      }
      chosen |= (1ull << bi);
      float sc = sgm[t * 65 + bi];
      i8[j] = bi;
      w8[j] = sc;
      wsum += sc;
    }
    const float inv = 1.f / (wsum + 1e-10f);
    const int tt = tok0 + t;
    float4 o;
    o.x = (float)i8[0]; o.y = (float)i8[1]; o.z = (float)i8[2]; o.w = (float)i8[3];
    *(float4*)(out + (size_t)tt * TOPK) = o;
    o.x = (float)i8[4]; o.y = (float)i8[5]; o.z = (float)i8[6]; o.w = (float)i8[7];
    *(float4*)(out + (size_t)tt * TOPK + 4) = o;
    o.x = w8[0] * inv; o.y = w8[1] * inv; o.z = w8[2] * inv; o.w = w8[3] * inv;
    *(float4*)(out + OFF_W + (size_t)tt * TOPK) = o;
    o.x = w8[4] * inv; o.y = w8[5] * inv; o.z = w8[6] * inv; o.w = w8[7] * inv;
    *(float4*)(out + OFF_W + (size_t)tt * TOPK + 4) = o;
#pragma unroll
    for (int j = 0; j < TOPK; ++j) atomicAdd(&csum[i8[j]], 1u);
    // wave-lockstep: all lanes' LDS atomics precede this read in program order
    atomicAdd(&Cacc[(b << 6) + lane], (float)csum[lane]);
  } else if (wv == 1) {
    // row sums of sigmoids -> rinv, then per-expert P partial
    const int t = lane;
    float ss = 0.f;
    for (int e = 0; e < NEXP; ++e) ss += sgm[t * 65 + e];
    rinvs[t] = 1.f / (ss + 1e-10f);
    // same-wave LDS RAW -> ordered via lgkmcnt
    float p = 0.f;
    for (int t2 = 0; t2 < 64; ++t2) p += sgm[t2 * 65 + lane] * rinvs[t2];
    atomicAdd(&Pacc[(b << 6) + lane], p);
  }

  __syncthreads();
  __threadfence();
  if (tid == 0) {
    int old = __hip_atomic_fetch_add(counter, 1, __ATOMIC_ACQ_REL,
                                     __HIP_MEMORY_SCOPE_AGENT);
    lastf = (old == 255) ? 1 : 0;
  }
  __syncthreads();

  if (lastf && tid < 64) {
    const int e = tid;
    float load = 0.f, partl = 0.f;
#pragma unroll
    for (int bb = 0; bb < NBATCH; ++bb) {
      float c = __hip_atomic_load(&Cacc[(bb << 6) + e], __ATOMIC_RELAXED,
                                  __HIP_MEMORY_SCOPE_AGENT);
      float p = __hip_atomic_load(&Pacc[(bb << 6) + e], __ATOMIC_RELAXED,
                                  __HIP_MEMORY_SCOPE_AGENT);
      load += c;
      partl += (c * (1.f / (TOPK * (float)SLEN))) * (p * (1.f / (float)SLEN));
    }
    out[OFF_LOAD + e] = load;
#pragma unroll
    for (int off = 32; off; off >>= 1) partl += __shfl_down(partl, off);
    if (e == 0) out[OFF_LOSS] = 0.01f * partl * (1.f / (float)NBATCH);
  }
}

// ---------------------------------------------------------------------------
extern "C" void kernel_launch(void* const* d_in, const int* in_sizes, int n_in,
                              void* d_out, int out_size, void* d_ws, size_t ws_size,
                              hipStream_t stream) {
  const float* x = (const float*)d_in[0];     // [4,4096,2048]
  const float* W = (const float*)d_in[1];     // [64,2048]
  const float* bias = (const float*)d_in[2];  // [64]
  float* out = (float*)d_out;

  float* ws = (float*)d_ws;
  float* Pacc = ws + WS_PACC;
  float* Cacc = ws + WS_CACC;
  int* counter = (int*)(ws + WS_CNT);
  ushort* Wh = (ushort*)(ws + WS_WH);
  ushort* Wl = (ushort*)(ws + WS_WL);

  hipMemsetAsync(ws, 0, 1024 * sizeof(float), stream);
  prep_w<<<128, 256, 0, stream>>>(W, Wh, Wl);
  gate_fused<<<256, 1024, 0, stream>>>(x, Wh, Wl, bias, out, Pacc, Cacc, counter);
}